// Round 2
// baseline (271.242 us; speedup 1.0000x reference)
//
#include <hip/hip_runtime.h>
#include <hip/hip_bf16.h>
#include <cstdint>

typedef __attribute__((ext_vector_type(8))) short bf16x8;
typedef __attribute__((ext_vector_type(4))) float f32x4;

#define LDT 72   // padded LDS row stride (bf16): 144B rows -> conflict-free ds_read_b128
#define PLDT 72

static __device__ __forceinline__ unsigned short f2bf(float x) {
    __hip_bfloat16 h = __float2bfloat16(x);   // RNE, compiles to v_cvt_pk_bf16_f32 when paired
    union { __hip_bfloat16 b; unsigned short u; } c; c.b = h; return c.u;
}
static __device__ __forceinline__ float bf2f(unsigned short b) {
    union { float f; uint32_t u; } v; v.u = ((uint32_t)b) << 16;
    return v.f;
}

// ---------------------------------------------------------------------------
// Projection GEMM: Y[m][e] = sum_k X[m][k] * W[e][k] + bias[e]
// M=4096, N=1024, K=1024. VTRANS=0: out (B,H,S,64) bf16. VTRANS=1: (B,H,64,S).
// ---------------------------------------------------------------------------
template <int VTRANS>
__global__ __launch_bounds__(256) void proj_gemm(const float* __restrict__ X,
                                                 const float* __restrict__ W,
                                                 const float* __restrict__ bias,
                                                 unsigned short* __restrict__ dst) {
    __shared__ unsigned short a_lds[128 * LDT];
    __shared__ unsigned short b_lds[128 * LDT];

    const int tid = threadIdx.x;
    const int lane = tid & 63;
    const int w = tid >> 6;
    const int lr = lane & 15;
    const int lg = lane >> 4;
    const int m0 = blockIdx.x * 128;
    const int e0 = blockIdx.y * 128;
    const int wrow = (w >> 1) * 64;
    const int wcol = (w & 1) * 64;

    f32x4 acc[4][4] = {};

    for (int k0 = 0; k0 < 1024; k0 += 64) {
        __syncthreads();
        for (int i = 0; i < 8; ++i) {
            int f = tid + 256 * i;
            int row = f >> 4;
            int c4 = (f & 15) << 2;
            float4 xa = *(const float4*)(X + (size_t)(m0 + row) * 1024 + k0 + c4);
            ushort4 pa;
            pa.x = f2bf(xa.x); pa.y = f2bf(xa.y); pa.z = f2bf(xa.z); pa.w = f2bf(xa.w);
            *(ushort4*)(a_lds + row * LDT + c4) = pa;
            float4 xb = *(const float4*)(W + (size_t)(e0 + row) * 1024 + k0 + c4);
            ushort4 pb;
            pb.x = f2bf(xb.x); pb.y = f2bf(xb.y); pb.z = f2bf(xb.z); pb.w = f2bf(xb.w);
            *(ushort4*)(b_lds + row * LDT + c4) = pb;
        }
        __syncthreads();

        for (int ks = 0; ks < 2; ++ks) {
            const int kk = ks * 32 + lg * 8;
            bf16x8 af[4], bfr[4];
            for (int mt = 0; mt < 4; ++mt)
                af[mt] = *(const bf16x8*)(a_lds + (wrow + mt * 16 + lr) * LDT + kk);
            for (int nt = 0; nt < 4; ++nt)
                bfr[nt] = *(const bf16x8*)(b_lds + (wcol + nt * 16 + lr) * LDT + kk);
            for (int mt = 0; mt < 4; ++mt)
                for (int nt = 0; nt < 4; ++nt)
                    acc[mt][nt] = __builtin_amdgcn_mfma_f32_16x16x32_bf16(
                        af[mt], bfr[nt], acc[mt][nt], 0, 0, 0);
        }
    }

    for (int mt = 0; mt < 4; ++mt)
        for (int nt = 0; nt < 4; ++nt)
            for (int i = 0; i < 4; ++i) {
                int m = m0 + wrow + mt * 16 + lg * 4 + i;
                int e = e0 + wcol + nt * 16 + lr;
                float val = acc[mt][nt][i] + bias[e];
                int b = m >> 11, s = m & 2047;
                int h = e >> 6, d = e & 63;
                if (VTRANS)
                    dst[(((size_t)b * 16 + h) * 64 + d) * 2048 + s] = f2bf(val);
                else
                    dst[(((size_t)b * 16 + h) * 2048 + s) * 64 + d] = f2bf(val);
            }
}

// ---------------------------------------------------------------------------
// Flash attention, swapped orientation. Block = 64 q rows of one (b,h);
// 4 waves x 16 q. S^T = K·Q^T (lane owns one q, 16 kv in-lane), softmax
// in-register, P^T via packed-b64 per-wave LDS, O^T = V^T·P^T.
// V comes pre-transposed from the projection: (B,H,64,S).
// ---------------------------------------------------------------------------
__global__ __launch_bounds__(256) void attn_kernel(const unsigned short* __restrict__ Qh,
                                                   const unsigned short* __restrict__ Kh,
                                                   const unsigned short* __restrict__ VTh,
                                                   const unsigned char* __restrict__ mask,
                                                   float* __restrict__ Out) {
    __shared__ union {
        unsigned short kv[2][64 * LDT];  // [0]=K rows [kv][d], [1]=V^T rows [d][kv]
        float ob[64 * 68];               // epilogue transpose buffer [q][d] stride 68
    } smem;
    __shared__ unsigned short p_lds[4][16 * PLDT];  // per-wave P [q][kv]

    const int tid = threadIdx.x;
    const int lane = tid & 63;
    const int w = tid >> 6;
    const int lr = lane & 15;
    const int lg = lane >> 4;
    const int q0 = blockIdx.x * 64;
    const int h = blockIdx.y;
    const int b = blockIdx.z;

    const size_t headoff = (((size_t)b * 16) + h) * 2048 * 64;
    const unsigned short* Qp = Qh + headoff;
    const unsigned short* Kp = Kh + headoff;
    const unsigned short* VTp = VTh + headoff;  // [64][2048]
    const unsigned char* maskp = mask + b * 2048;

    // Q as B-operand: lane holds q = lr, d = ks*32 + lg*8 + j  (scaled)
    const float qscale = 0.125f * 1.44269504088896340736f;  // 1/sqrt(64) * log2(e)
    bf16x8 qf[2];
    {
        int row = q0 + w * 16 + lr;
        for (int ks = 0; ks < 2; ++ks) {
            bf16x8 t = *(const bf16x8*)(Qp + (size_t)row * 64 + ks * 32 + lg * 8);
            for (int j = 0; j < 8; ++j)
                t[j] = (short)f2bf(bf2f((unsigned short)t[j]) * qscale);
            qf[ks] = t;
        }
    }

    f32x4 o[4] = {};          // O^T: lane holds q=lr, d = mt*16 + lg*4 + i
    float mrow = -INFINITY;   // running max for q=lr (log2 domain)
    float lsum = 0.f;

    for (int t = 0; t < 32; ++t) {
        const int kv0 = t * 64;
        __syncthreads();
        for (int i = 0; i < 2; ++i) {
            int c = tid + 256 * i;
            int row = c >> 3;
            int off = (c & 7) * 8;
            *(uint4*)(smem.kv[0] + row * LDT + off) =
                *(const uint4*)(Kp + (size_t)(kv0 + row) * 64 + off);
            *(uint4*)(smem.kv[1] + row * LDT + off) =
                *(const uint4*)(VTp + (size_t)row * 2048 + kv0 + off);
        }
        __syncthreads();

        unsigned long long mbits = __ballot(maskp[kv0 + lane] != 0);

        // S^T[kv][q]: A = K rows (kv), B = Q
        f32x4 s[4] = {};
        for (int ks = 0; ks < 2; ++ks) {
            const int kk = ks * 32 + lg * 8;
            for (int mt = 0; mt < 4; ++mt) {
                bf16x8 kf = *(const bf16x8*)(smem.kv[0] + (mt * 16 + lr) * LDT + kk);
                s[mt] = __builtin_amdgcn_mfma_f32_16x16x32_bf16(kf, qf[ks], s[mt], 0, 0, 0);
            }
        }
        if (mbits) {
            for (int mt = 0; mt < 4; ++mt)
                for (int i = 0; i < 4; ++i)
                    if ((mbits >> (mt * 16 + lg * 4 + i)) & 1ull) s[mt][i] = -1e30f;
        }

        // online softmax: lane owns q=lr; 16 kv in-lane + lanes lg=0..3 share q
        float mx = s[0][0];
        for (int mt = 0; mt < 4; ++mt)
            for (int i = 0; i < 4; ++i) mx = fmaxf(mx, s[mt][i]);
        mx = fmaxf(mx, __shfl_xor(mx, 16));
        mx = fmaxf(mx, __shfl_xor(mx, 32));
        if (!__all(mx <= mrow + 8.0f)) {  // defer-max (T13)
            float nm = fmaxf(mrow, mx);
            float f = exp2f(mrow - nm);
            mrow = nm;
            lsum *= f;
            for (int mt = 0; mt < 4; ++mt)
                for (int i = 0; i < 4; ++i) o[mt][i] *= f;
        }
        float p[4][4];
        float ls = 0.f;
        for (int mt = 0; mt < 4; ++mt)
            for (int i = 0; i < 4; ++i) {
                p[mt][i] = exp2f(s[mt][i] - mrow);
                ls += p[mt][i];
            }
        ls += __shfl_xor(ls, 16);
        ls += __shfl_xor(ls, 32);
        lsum += ls;

        // P^T -> per-wave LDS, packed: row q=lr, kv = mt*16 + lg*4 + {0..3}
        for (int mt = 0; mt < 4; ++mt) {
            uint2 pr;
            pr.x = (unsigned int)f2bf(p[mt][0]) | ((unsigned int)f2bf(p[mt][1]) << 16);
            pr.y = (unsigned int)f2bf(p[mt][2]) | ((unsigned int)f2bf(p[mt][3]) << 16);
            *(uint2*)(&p_lds[w][lr * PLDT + mt * 16 + lg * 4]) = pr;
        }

        // O^T += V^T · P^T : A = V^T rows (d), B = P^T (lane reads its q row)
        for (int ks = 0; ks < 2; ++ks) {
            const int kk = ks * 32 + lg * 8;
            bf16x8 pfr = *(const bf16x8*)(&p_lds[w][lr * PLDT + kk]);
            for (int mt = 0; mt < 4; ++mt) {
                bf16x8 vf = *(const bf16x8*)(smem.kv[1] + (mt * 16 + lr) * LDT + kk);
                o[mt] = __builtin_amdgcn_mfma_f32_16x16x32_bf16(vf, pfr, o[mt], 0, 0, 0);
            }
        }
    }

    // epilogue: transpose O^T -> [q][d] in LDS, then coalesced float4 stores
    float rinv = 1.0f / lsum;
    __syncthreads();
    for (int mt = 0; mt < 4; ++mt)
        for (int i = 0; i < 4; ++i) {
            int d = mt * 16 + lg * 4 + i;
            smem.ob[(w * 16 + lr) * 68 + d] = o[mt][i] * rinv;
        }
    __syncthreads();
    for (int j = 0; j < 4; ++j) {
        int id = tid + 256 * j;        // 1024 float4s = 64 q x 16
        int row = id >> 4;
        int c4 = (id & 15) << 2;
        float4 val = *(const float4*)(&smem.ob[row * 68 + c4]);
        *(float4*)(&Out[((size_t)b * 2048 + q0 + row) * 1024 + h * 64 + c4]) = val;
    }
}

extern "C" void kernel_launch(void* const* d_in, const int* in_sizes, int n_in,
                              void* d_out, int out_size, void* d_ws, size_t ws_size,
                              hipStream_t stream) {
    const float* v = (const float*)d_in[0];
    const float* k = (const float*)d_in[1];
    const float* q = (const float*)d_in[2];
    const unsigned char* mask = (const unsigned char*)d_in[3];
    const float* Wq = (const float*)d_in[4];
    const float* bq = (const float*)d_in[5];
    const float* Wk = (const float*)d_in[6];
    const float* bk = (const float*)d_in[7];
    const float* Wv = (const float*)d_in[8];
    const float* bv = (const float*)d_in[9];
    float* out = (float*)d_out;

    unsigned short* qws = (unsigned short*)d_ws;
    unsigned short* kws = qws + 4194304;
    unsigned short* vws = kws + 4194304;

    dim3 pgrid(32, 8, 1);
    proj_gemm<0><<<pgrid, 256, 0, stream>>>(q, Wq, bq, qws);
    proj_gemm<0><<<pgrid, 256, 0, stream>>>(k, Wk, bk, kws);
    proj_gemm<1><<<pgrid, 256, 0, stream>>>(v, Wv, bv, vws);

    dim3 agrid(32, 16, 2);
    attn_kernel<<<agrid, 256, 0, stream>>>(qws, kws, vws, mask, out);
}

// Round 3
// 211.685 us; speedup vs baseline: 1.2813x; 1.2813x over previous
//
#include <hip/hip_runtime.h>
#include <hip/hip_bf16.h>
#include <cstdint>

typedef __attribute__((ext_vector_type(8))) short bf16x8;
typedef __attribute__((ext_vector_type(4))) float f32x4;

#define LDT 72    // proj LDS row stride (bf16)
#define PLDT 72   // attn P^T LDS row stride (bf16)

static __device__ __forceinline__ unsigned short f2bf(float x) {
    __hip_bfloat16 h = __float2bfloat16(x);
    union { __hip_bfloat16 b; unsigned short u; } c; c.b = h; return c.u;
}
static __device__ __forceinline__ float bf2f(unsigned short b) {
    union { float f; uint32_t u; } v; v.u = ((uint32_t)b) << 16;
    return v.f;
}

// ---------------------------------------------------------------------------
// Projection GEMM: Y[m][e] = sum_k X[m][k] * W[e][k] + bias[e]
// M=4096, N=1024, K=1024. VTRANS=0: out (B,H,S,64) bf16. VTRANS=1: (B,H,64,S).
// ---------------------------------------------------------------------------
template <int VTRANS>
__global__ __launch_bounds__(256) void proj_gemm(const float* __restrict__ X,
                                                 const float* __restrict__ W,
                                                 const float* __restrict__ bias,
                                                 unsigned short* __restrict__ dst) {
    __shared__ unsigned short a_lds[128 * LDT];
    __shared__ unsigned short b_lds[128 * LDT];

    const int tid = threadIdx.x;
    const int lane = tid & 63;
    const int w = tid >> 6;
    const int lr = lane & 15;
    const int lg = lane >> 4;
    const int m0 = blockIdx.x * 128;
    const int e0 = blockIdx.y * 128;
    const int wrow = (w >> 1) * 64;
    const int wcol = (w & 1) * 64;

    f32x4 acc[4][4] = {};

    for (int k0 = 0; k0 < 1024; k0 += 64) {
        __syncthreads();
        for (int i = 0; i < 8; ++i) {
            int f = tid + 256 * i;
            int row = f >> 4;
            int c4 = (f & 15) << 2;
            float4 xa = *(const float4*)(X + (size_t)(m0 + row) * 1024 + k0 + c4);
            ushort4 pa;
            pa.x = f2bf(xa.x); pa.y = f2bf(xa.y); pa.z = f2bf(xa.z); pa.w = f2bf(xa.w);
            *(ushort4*)(a_lds + row * LDT + c4) = pa;
            float4 xb = *(const float4*)(W + (size_t)(e0 + row) * 1024 + k0 + c4);
            ushort4 pb;
            pb.x = f2bf(xb.x); pb.y = f2bf(xb.y); pb.z = f2bf(xb.z); pb.w = f2bf(xb.w);
            *(ushort4*)(b_lds + row * LDT + c4) = pb;
        }
        __syncthreads();

        for (int ks = 0; ks < 2; ++ks) {
            const int kk = ks * 32 + lg * 8;
            bf16x8 af[4], bfr[4];
            for (int mt = 0; mt < 4; ++mt)
                af[mt] = *(const bf16x8*)(a_lds + (wrow + mt * 16 + lr) * LDT + kk);
            for (int nt = 0; nt < 4; ++nt)
                bfr[nt] = *(const bf16x8*)(b_lds + (wcol + nt * 16 + lr) * LDT + kk);
            for (int mt = 0; mt < 4; ++mt)
                for (int nt = 0; nt < 4; ++nt)
                    acc[mt][nt] = __builtin_amdgcn_mfma_f32_16x16x32_bf16(
                        af[mt], bfr[nt], acc[mt][nt], 0, 0, 0);
        }
    }

    for (int mt = 0; mt < 4; ++mt)
        for (int nt = 0; nt < 4; ++nt)
            for (int i = 0; i < 4; ++i) {
                int m = m0 + wrow + mt * 16 + lg * 4 + i;
                int e = e0 + wcol + nt * 16 + lr;
                float val = acc[mt][nt][i] + bias[e];
                int b = m >> 11, s = m & 2047;
                int h = e >> 6, d = e & 63;
                if (VTRANS)
                    dst[(((size_t)b * 16 + h) * 64 + d) * 2048 + s] = f2bf(val);
                else
                    dst[(((size_t)b * 16 + h) * 2048 + s) * 64 + d] = f2bf(val);
            }
}

// ---------------------------------------------------------------------------
// Flash attention v3: barrier-free. Block = 4 independent waves; each wave
// owns 32 q rows (two 16-row fragments) of one (b,h). K/V MFMA fragments are
// read DIRECTLY from global (L2-resident: 512KB/head, shared by 16 blocks on
// one XCD via T1 swizzle). Swapped orientation: S^T = K·Q^T, softmax
// in-register, P^T via per-wave LDS, O^T = V^T·P^T.
// ---------------------------------------------------------------------------
__global__ __launch_bounds__(256) void attn_kernel(const unsigned short* __restrict__ Qh,
                                                   const unsigned short* __restrict__ Kh,
                                                   const unsigned short* __restrict__ VTh,
                                                   const unsigned char* __restrict__ mask,
                                                   float* __restrict__ Out) {
    __shared__ unsigned short pbuf[4][32 * PLDT];  // per-wave P^T [q 32][kv 64]

    const int tid = threadIdx.x;
    const int lane = tid & 63;
    const int w = tid >> 6;
    const int lr = lane & 15;
    const int lg = lane >> 4;

    // T1 XCD swizzle: 512 workgroups, 64 per XCD chunk -> one (b,h)'s 16
    // q-blocks stay on one XCD.
    const int bid = blockIdx.x;
    const int wk = (bid & 7) * 64 + (bid >> 3);
    const int x = wk & 15;        // q-tile (128 q each)
    const int bh = wk >> 4;       // 0..31
    const int h = bh & 15;
    const int b = bh >> 4;
    const int q0 = x * 128;

    const size_t headoff = (((size_t)b * 16) + h) * 2048 * 64;
    const unsigned short* Qp = Qh + headoff;
    const unsigned short* Kp = Kh + headoff;
    const unsigned short* VTp = VTh + headoff;  // [64][2048]
    const unsigned char* maskp = mask + b * 2048;
    unsigned short* pw = pbuf[w];

    // per-lane fragment base pointers
    const unsigned short* Klane = Kp + lr * 64 + lg * 8;     // + (kv0+mt*16)*64 + ks*32
    const unsigned short* Vlane = VTp + lr * 2048 + lg * 8;  // + mt*16*2048 + kv0 + ks*32

    // Q as B-operand (col=q=lr, k=lg*8+j), scaled by 1/sqrt(64)*log2(e)
    const float qscale = 0.125f * 1.44269504088896340736f;
    bf16x8 qf[2][2];  // [qh][ks]
#pragma unroll
    for (int qh = 0; qh < 2; ++qh) {
        int row = q0 + w * 32 + qh * 16 + lr;
#pragma unroll
        for (int ks = 0; ks < 2; ++ks) {
            bf16x8 t = *(const bf16x8*)(Qp + (size_t)row * 64 + ks * 32 + lg * 8);
#pragma unroll
            for (int j = 0; j < 8; ++j)
                t[j] = (short)f2bf(bf2f((unsigned short)t[j]) * qscale);
            qf[qh][ks] = t;
        }
    }

    f32x4 o[2][4] = {};   // O^T: lane holds q=lr, d = mt*16 + lg*4 + i
    float mrow[2] = {-INFINITY, -INFINITY};
    float lsum[2] = {0.f, 0.f};

    for (int t = 0; t < 32; ++t) {
        const int kv0 = t * 64;

        // K fragments (8 x b128 direct from global/L2)
        bf16x8 kf[2][4];
#pragma unroll
        for (int ks = 0; ks < 2; ++ks)
#pragma unroll
            for (int mt = 0; mt < 4; ++mt)
                kf[ks][mt] = *(const bf16x8*)(Klane + (size_t)(kv0 + mt * 16) * 64 + ks * 32);

        // S^T[kv][q] = K . Q^T
        f32x4 s[2][4] = {};
        __builtin_amdgcn_s_setprio(1);
#pragma unroll
        for (int ks = 0; ks < 2; ++ks)
#pragma unroll
            for (int mt = 0; mt < 4; ++mt) {
                s[0][mt] = __builtin_amdgcn_mfma_f32_16x16x32_bf16(kf[ks][mt], qf[0][ks], s[0][mt], 0, 0, 0);
                s[1][mt] = __builtin_amdgcn_mfma_f32_16x16x32_bf16(kf[ks][mt], qf[1][ks], s[1][mt], 0, 0, 0);
            }
        __builtin_amdgcn_s_setprio(0);

        // V fragments: issue now so HBM/L2 latency hides under softmax
        bf16x8 vf[2][4];
#pragma unroll
        for (int ks = 0; ks < 2; ++ks)
#pragma unroll
            for (int mt = 0; mt < 4; ++mt)
                vf[ks][mt] = *(const bf16x8*)(Vlane + (size_t)mt * 16 * 2048 + kv0 + ks * 32);

        unsigned long long mbits = __ballot(maskp[kv0 + lane] != 0);
        if (mbits) {
#pragma unroll
            for (int qh = 0; qh < 2; ++qh)
#pragma unroll
                for (int mt = 0; mt < 4; ++mt)
#pragma unroll
                    for (int i = 0; i < 4; ++i)
                        if ((mbits >> (mt * 16 + lg * 4 + i)) & 1ull) s[qh][mt][i] = -1e30f;
        }

        // online softmax per q-half (lane owns q=lr; lanes lg=0..3 share q)
#pragma unroll
        for (int qh = 0; qh < 2; ++qh) {
            float mx = s[qh][0][0];
#pragma unroll
            for (int mt = 0; mt < 4; ++mt)
#pragma unroll
                for (int i = 0; i < 4; ++i) mx = fmaxf(mx, s[qh][mt][i]);
            mx = fmaxf(mx, __shfl_xor(mx, 16));
            mx = fmaxf(mx, __shfl_xor(mx, 32));
            if (!__all(mx <= mrow[qh] + 8.0f)) {  // defer-max (T13)
                float nm = fmaxf(mrow[qh], mx);
                float f = exp2f(mrow[qh] - nm);
                mrow[qh] = nm;
                lsum[qh] *= f;
#pragma unroll
                for (int mt = 0; mt < 4; ++mt)
#pragma unroll
                    for (int i = 0; i < 4; ++i) o[qh][mt][i] *= f;
            }
            float ls = 0.f;
            float p[4][4];
#pragma unroll
            for (int mt = 0; mt < 4; ++mt)
#pragma unroll
                for (int i = 0; i < 4; ++i) {
                    p[mt][i] = exp2f(s[qh][mt][i] - mrow[qh]);
                    ls += p[mt][i];
                }
            ls += __shfl_xor(ls, 16);
            ls += __shfl_xor(ls, 32);
            lsum[qh] += ls;

            // P^T -> per-wave LDS: row q = qh*16+lr, kv = mt*16 + lg*4 + {0..3}
#pragma unroll
            for (int mt = 0; mt < 4; ++mt) {
                uint2 pr;
                pr.x = (unsigned int)f2bf(p[mt][0]) | ((unsigned int)f2bf(p[mt][1]) << 16);
                pr.y = (unsigned int)f2bf(p[mt][2]) | ((unsigned int)f2bf(p[mt][3]) << 16);
                *(uint2*)(&pw[(qh * 16 + lr) * PLDT + mt * 16 + lg * 4]) = pr;
            }
        }

        // O^T += V^T . P^T
        __builtin_amdgcn_s_setprio(1);
#pragma unroll
        for (int qh = 0; qh < 2; ++qh)
#pragma unroll
            for (int ks = 0; ks < 2; ++ks) {
                bf16x8 pfr = *(const bf16x8*)(&pw[(qh * 16 + lr) * PLDT + ks * 32 + lg * 8]);
#pragma unroll
                for (int mt = 0; mt < 4; ++mt)
                    o[qh][mt] = __builtin_amdgcn_mfma_f32_16x16x32_bf16(vf[ks][mt], pfr, o[qh][mt], 0, 0, 0);
            }
        __builtin_amdgcn_s_setprio(0);
    }

    // epilogue (wave-private, reuses this wave's P buffer): transpose O^T ->
    // [q][d] then coalesced float4 stores
    float* ep = (float*)pw;  // 16*68 floats = 4352B <= 4608B
#pragma unroll
    for (int qh = 0; qh < 2; ++qh) {
        float rinv = 1.0f / lsum[qh];
#pragma unroll
        for (int mt = 0; mt < 4; ++mt)
#pragma unroll
            for (int i = 0; i < 4; ++i)
                ep[lr * 68 + mt * 16 + lg * 4 + i] = o[qh][mt][i] * rinv;
#pragma unroll
        for (int j = 0; j < 4; ++j) {
            int id = lane + 64 * j;     // 256 float4 = 16 q x 16
            int row = id >> 4;
            int c4 = (id & 15) << 2;
            float4 val = *(const float4*)(&ep[row * 68 + c4]);
            *(float4*)(&Out[((size_t)b * 2048 + q0 + w * 32 + qh * 16 + row) * 1024 + h * 64 + c4]) = val;
        }
    }
}

extern "C" void kernel_launch(void* const* d_in, const int* in_sizes, int n_in,
                              void* d_out, int out_size, void* d_ws, size_t ws_size,
                              hipStream_t stream) {
    const float* v = (const float*)d_in[0];
    const float* k = (const float*)d_in[1];
    const float* q = (const float*)d_in[2];
    const unsigned char* mask = (const unsigned char*)d_in[3];
    const float* Wq = (const float*)d_in[4];
    const float* bq = (const float*)d_in[5];
    const float* Wk = (const float*)d_in[6];
    const float* bk = (const float*)d_in[7];
    const float* Wv = (const float*)d_in[8];
    const float* bv = (const float*)d_in[9];
    float* out = (float*)d_out;

    unsigned short* qws = (unsigned short*)d_ws;
    unsigned short* kws = qws + 4194304;
    unsigned short* vws = kws + 4194304;

    dim3 pgrid(32, 8, 1);
    proj_gemm<0><<<pgrid, 256, 0, stream>>>(q, Wq, bq, qws);
    proj_gemm<0><<<pgrid, 256, 0, stream>>>(k, Wk, bk, kws);
    proj_gemm<1><<<pgrid, 256, 0, stream>>>(v, Wv, bv, vws);

    attn_kernel<<<dim3(512), 256, 0, stream>>>(qws, kws, vws, mask, out);
}

// Round 4
// 189.137 us; speedup vs baseline: 1.4341x; 1.1192x over previous
//
#include <hip/hip_runtime.h>
#include <hip/hip_bf16.h>
#include <cstdint>

typedef __attribute__((ext_vector_type(8))) short bf16x8;
typedef __attribute__((ext_vector_type(4))) float f32x4;

#define LDT 72    // proj LDS row stride (bf16)
#define PLDT 72   // attn P^T LDS row stride (bf16)

static __device__ __forceinline__ unsigned short f2bf(float x) {
    __hip_bfloat16 h = __float2bfloat16(x);
    union { __hip_bfloat16 b; unsigned short u; } c; c.b = h; return c.u;
}
static __device__ __forceinline__ float bf2f(unsigned short b) {
    union { float f; uint32_t u; } v; v.u = ((uint32_t)b) << 16;
    return v.f;
}

// ---------------------------------------------------------------------------
// Fused projection GEMMs: z=0: Q, z=1: K (both (B,H,S,64)), z=2: V^T (B,H,64,S)
// Y[m][e] = sum_k X[m][k] * W[e][k] + bias[e].  M=4096, N=1024, K=1024.
// One dispatch, grid (32,8,3) = 768 blocks -> 3 blocks/CU.
// ---------------------------------------------------------------------------
__global__ __launch_bounds__(256) void proj_gemm_all(
    const float* __restrict__ Xq, const float* __restrict__ Xk, const float* __restrict__ Xv,
    const float* __restrict__ Wqp, const float* __restrict__ Wkp, const float* __restrict__ Wvp,
    const float* __restrict__ bqp, const float* __restrict__ bkp, const float* __restrict__ bvp,
    unsigned short* __restrict__ dq, unsigned short* __restrict__ dk, unsigned short* __restrict__ dv) {
    __shared__ unsigned short a_lds[128 * LDT];
    __shared__ unsigned short b_lds[128 * LDT];

    const int z = blockIdx.z;
    const float* X = (z == 0) ? Xq : (z == 1) ? Xk : Xv;
    const float* W = (z == 0) ? Wqp : (z == 1) ? Wkp : Wvp;
    const float* bias = (z == 0) ? bqp : (z == 1) ? bkp : bvp;
    unsigned short* dst = (z == 0) ? dq : (z == 1) ? dk : dv;
    const bool vtrans = (z == 2);

    const int tid = threadIdx.x;
    const int lane = tid & 63;
    const int w = tid >> 6;
    const int lr = lane & 15;
    const int lg = lane >> 4;
    const int m0 = blockIdx.x * 128;
    const int e0 = blockIdx.y * 128;
    const int wrow = (w >> 1) * 64;
    const int wcol = (w & 1) * 64;

    f32x4 acc[4][4] = {};

    for (int k0 = 0; k0 < 1024; k0 += 64) {
        __syncthreads();
        for (int i = 0; i < 8; ++i) {
            int f = tid + 256 * i;
            int row = f >> 4;
            int c4 = (f & 15) << 2;
            float4 xa = *(const float4*)(X + (size_t)(m0 + row) * 1024 + k0 + c4);
            ushort4 pa;
            pa.x = f2bf(xa.x); pa.y = f2bf(xa.y); pa.z = f2bf(xa.z); pa.w = f2bf(xa.w);
            *(ushort4*)(a_lds + row * LDT + c4) = pa;
            float4 xb = *(const float4*)(W + (size_t)(e0 + row) * 1024 + k0 + c4);
            ushort4 pb;
            pb.x = f2bf(xb.x); pb.y = f2bf(xb.y); pb.z = f2bf(xb.z); pb.w = f2bf(xb.w);
            *(ushort4*)(b_lds + row * LDT + c4) = pb;
        }
        __syncthreads();

        for (int ks = 0; ks < 2; ++ks) {
            const int kk = ks * 32 + lg * 8;
            bf16x8 af[4], bfr[4];
            for (int mt = 0; mt < 4; ++mt)
                af[mt] = *(const bf16x8*)(a_lds + (wrow + mt * 16 + lr) * LDT + kk);
            for (int nt = 0; nt < 4; ++nt)
                bfr[nt] = *(const bf16x8*)(b_lds + (wcol + nt * 16 + lr) * LDT + kk);
            for (int mt = 0; mt < 4; ++mt)
                for (int nt = 0; nt < 4; ++nt)
                    acc[mt][nt] = __builtin_amdgcn_mfma_f32_16x16x32_bf16(
                        af[mt], bfr[nt], acc[mt][nt], 0, 0, 0);
        }
    }

    for (int mt = 0; mt < 4; ++mt)
        for (int nt = 0; nt < 4; ++nt)
            for (int i = 0; i < 4; ++i) {
                int m = m0 + wrow + mt * 16 + lg * 4 + i;
                int e = e0 + wcol + nt * 16 + lr;
                float val = acc[mt][nt][i] + bias[e];
                int b = m >> 11, s = m & 2047;
                int h = e >> 6, d = e & 63;
                if (vtrans)
                    dst[(((size_t)b * 16 + h) * 64 + d) * 2048 + s] = f2bf(val);
                else
                    dst[(((size_t)b * 16 + h) * 2048 + s) * 64 + d] = f2bf(val);
            }
}

// ---------------------------------------------------------------------------
// Flash attention v4: barrier-free + K register double-buffer pipeline.
// Block = 4 independent waves; each wave owns 32 q rows of one (b,h).
// K/V fragments direct from global (L2-resident via T1 XCD swizzle).
// S^T = K·Q^T, in-register online softmax, P^T via per-wave LDS, O^T = V^T·P^T.
// ---------------------------------------------------------------------------
__device__ __forceinline__ void load_k(bf16x8 (&kf)[2][4],
                                       const unsigned short* Klane, int kv0) {
#pragma unroll
    for (int ks = 0; ks < 2; ++ks)
#pragma unroll
        for (int mt = 0; mt < 4; ++mt)
            kf[ks][mt] = *(const bf16x8*)(Klane + (size_t)(kv0 + mt * 16) * 64 + ks * 32);
}

__device__ __forceinline__ void attn_step(const bf16x8 (&kf)[2][4],
                                          const bf16x8 (&qf)[2][2],
                                          const unsigned short* Vlane, int kv0,
                                          unsigned char mbyte,
                                          f32x4 (&o)[2][4], float (&mrow)[2],
                                          float (&lsum)[2], unsigned short* pw,
                                          int lr, int lg) {
    // S^T[kv][q] = K . Q^T
    f32x4 s[2][4] = {};
    __builtin_amdgcn_s_setprio(1);
#pragma unroll
    for (int ks = 0; ks < 2; ++ks)
#pragma unroll
        for (int mt = 0; mt < 4; ++mt) {
            s[0][mt] = __builtin_amdgcn_mfma_f32_16x16x32_bf16(kf[ks][mt], qf[0][ks], s[0][mt], 0, 0, 0);
            s[1][mt] = __builtin_amdgcn_mfma_f32_16x16x32_bf16(kf[ks][mt], qf[1][ks], s[1][mt], 0, 0, 0);
        }
    __builtin_amdgcn_s_setprio(0);

    // V fragments: issue now; consumed after softmax (~400 cyc cover)
    bf16x8 vf[2][4];
#pragma unroll
    for (int ks = 0; ks < 2; ++ks)
#pragma unroll
        for (int mt = 0; mt < 4; ++mt)
            vf[ks][mt] = *(const bf16x8*)(Vlane + (size_t)mt * 16 * 2048 + kv0 + ks * 32);

    unsigned long long mbits = __ballot(mbyte != 0);
    if (mbits) {
#pragma unroll
        for (int qh = 0; qh < 2; ++qh)
#pragma unroll
            for (int mt = 0; mt < 4; ++mt)
#pragma unroll
                for (int i = 0; i < 4; ++i)
                    if ((mbits >> (mt * 16 + lg * 4 + i)) & 1ull) s[qh][mt][i] = -1e30f;
    }

    // online softmax per q-half (lane owns q=lr; lanes lg=0..3 share q)
#pragma unroll
    for (int qh = 0; qh < 2; ++qh) {
        float mx = s[qh][0][0];
#pragma unroll
        for (int mt = 0; mt < 4; ++mt)
#pragma unroll
            for (int i = 0; i < 4; ++i) mx = fmaxf(mx, s[qh][mt][i]);
        mx = fmaxf(mx, __shfl_xor(mx, 16));
        mx = fmaxf(mx, __shfl_xor(mx, 32));
        if (!__all(mx <= mrow[qh] + 8.0f)) {  // defer-max (T13)
            float nm = fmaxf(mrow[qh], mx);
            float f = exp2f(mrow[qh] - nm);
            mrow[qh] = nm;
            lsum[qh] *= f;
#pragma unroll
            for (int mt = 0; mt < 4; ++mt)
#pragma unroll
                for (int i = 0; i < 4; ++i) o[qh][mt][i] *= f;
        }
        float ls = 0.f;
        float p[4][4];
#pragma unroll
        for (int mt = 0; mt < 4; ++mt)
#pragma unroll
            for (int i = 0; i < 4; ++i) {
                p[mt][i] = exp2f(s[qh][mt][i] - mrow[qh]);
                ls += p[mt][i];
            }
        ls += __shfl_xor(ls, 16);
        ls += __shfl_xor(ls, 32);
        lsum[qh] += ls;

        // P^T -> per-wave LDS: row q = qh*16+lr, kv = mt*16 + lg*4 + {0..3}
#pragma unroll
        for (int mt = 0; mt < 4; ++mt) {
            uint2 pr;
            pr.x = (unsigned int)f2bf(p[mt][0]) | ((unsigned int)f2bf(p[mt][1]) << 16);
            pr.y = (unsigned int)f2bf(p[mt][2]) | ((unsigned int)f2bf(p[mt][3]) << 16);
            *(uint2*)(&pw[(qh * 16 + lr) * PLDT + mt * 16 + lg * 4]) = pr;
        }
    }

    // O^T += V^T . P^T
    __builtin_amdgcn_s_setprio(1);
#pragma unroll
    for (int qh = 0; qh < 2; ++qh)
#pragma unroll
        for (int ks = 0; ks < 2; ++ks) {
            bf16x8 pfr = *(const bf16x8*)(&pw[(qh * 16 + lr) * PLDT + ks * 32 + lg * 8]);
#pragma unroll
            for (int mt = 0; mt < 4; ++mt)
                o[qh][mt] = __builtin_amdgcn_mfma_f32_16x16x32_bf16(vf[ks][mt], pfr, o[qh][mt], 0, 0, 0);
        }
    __builtin_amdgcn_s_setprio(0);
}

__global__ __launch_bounds__(256) void attn_kernel(const unsigned short* __restrict__ Qh,
                                                   const unsigned short* __restrict__ Kh,
                                                   const unsigned short* __restrict__ VTh,
                                                   const unsigned char* __restrict__ mask,
                                                   float* __restrict__ Out) {
    __shared__ unsigned short pbuf[4][32 * PLDT];  // per-wave P^T [q 32][kv 64]

    const int tid = threadIdx.x;
    const int lane = tid & 63;
    const int w = tid >> 6;
    const int lr = lane & 15;
    const int lg = lane >> 4;

    // T1 XCD swizzle: 512 workgroups, 64 per XCD chunk
    const int bid = blockIdx.x;
    const int wk = (bid & 7) * 64 + (bid >> 3);
    const int x = wk & 15;
    const int bh = wk >> 4;
    const int h = bh & 15;
    const int b = bh >> 4;
    const int q0 = x * 128;

    const size_t headoff = (((size_t)b * 16) + h) * 2048 * 64;
    const unsigned short* Qp = Qh + headoff;
    const unsigned short* Kp = Kh + headoff;
    const unsigned short* VTp = VTh + headoff;  // [64][2048]
    const unsigned char* maskp = mask + b * 2048;
    unsigned short* pw = pbuf[w];

    const unsigned short* Klane = Kp + lr * 64 + lg * 8;
    const unsigned short* Vlane = VTp + lr * 2048 + lg * 8;

    // Q as B-operand (col=q=lr, k=lg*8+j), scaled by 1/sqrt(64)*log2(e)
    const float qscale = 0.125f * 1.44269504088896340736f;
    bf16x8 qf[2][2];
#pragma unroll
    for (int qh = 0; qh < 2; ++qh) {
        int row = q0 + w * 32 + qh * 16 + lr;
#pragma unroll
        for (int ks = 0; ks < 2; ++ks) {
            bf16x8 t = *(const bf16x8*)(Qp + (size_t)row * 64 + ks * 32 + lg * 8);
#pragma unroll
            for (int j = 0; j < 8; ++j)
                t[j] = (short)f2bf(bf2f((unsigned short)t[j]) * qscale);
            qf[qh][ks] = t;
        }
    }

    f32x4 o[2][4] = {};
    float mrow[2] = {-INFINITY, -INFINITY};
    float lsum[2] = {0.f, 0.f};

    // K register double-buffer pipeline
    bf16x8 kfA[2][4], kfB[2][4];
    load_k(kfA, Klane, 0);
    unsigned char mbA = maskp[lane];
    unsigned char mbB;

#pragma unroll 1
    for (int t = 0; t < 32; t += 2) {
        // prefetch K(t+1) + mask(t+1) before consuming kfA
        load_k(kfB, Klane, (t + 1) * 64);
        mbB = maskp[(t + 1) * 64 + lane];
        attn_step(kfA, qf, Vlane, t * 64, mbA, o, mrow, lsum, pw, lr, lg);

        int tn = (t + 2 < 32) ? (t + 2) : 31;  // clamped tail prefetch (harmless)
        load_k(kfA, Klane, tn * 64);
        mbA = maskp[tn * 64 + lane];
        attn_step(kfB, qf, Vlane, (t + 1) * 64, mbB, o, mrow, lsum, pw, lr, lg);
    }

    // epilogue (wave-private): transpose O^T -> [q][d] then coalesced stores
    float* ep = (float*)pw;
#pragma unroll
    for (int qh = 0; qh < 2; ++qh) {
        float rinv = 1.0f / lsum[qh];
#pragma unroll
        for (int mt = 0; mt < 4; ++mt)
#pragma unroll
            for (int i = 0; i < 4; ++i)
                ep[lr * 68 + mt * 16 + lg * 4 + i] = o[qh][mt][i] * rinv;
#pragma unroll
        for (int j = 0; j < 4; ++j) {
            int id = lane + 64 * j;
            int row = id >> 4;
            int c4 = (id & 15) << 2;
            float4 val = *(const float4*)(&ep[row * 68 + c4]);
            *(float4*)(&Out[((size_t)b * 2048 + q0 + w * 32 + qh * 16 + row) * 1024 + h * 64 + c4]) = val;
        }
    }
}

extern "C" void kernel_launch(void* const* d_in, const int* in_sizes, int n_in,
                              void* d_out, int out_size, void* d_ws, size_t ws_size,
                              hipStream_t stream) {
    const float* v = (const float*)d_in[0];
    const float* k = (const float*)d_in[1];
    const float* q = (const float*)d_in[2];
    const unsigned char* mask = (const unsigned char*)d_in[3];
    const float* Wq = (const float*)d_in[4];
    const float* bq = (const float*)d_in[5];
    const float* Wk = (const float*)d_in[6];
    const float* bk = (const float*)d_in[7];
    const float* Wv = (const float*)d_in[8];
    const float* bv = (const float*)d_in[9];
    float* out = (float*)d_out;

    unsigned short* qws = (unsigned short*)d_ws;
    unsigned short* kws = qws + 4194304;
    unsigned short* vws = kws + 4194304;

    dim3 pgrid(32, 8, 3);
    proj_gemm_all<<<pgrid, 256, 0, stream>>>(q, k, v, Wq, Wk, Wv, bq, bk, bv,
                                             qws, kws, vws);

    attn_kernel<<<dim3(512), 256, 0, stream>>>(qws, kws, vws, mask, out);
}